// Round 3
// baseline (764.207 us; speedup 1.0000x reference)
//
#include <hip/hip_runtime.h>
#include <hip/hip_bf16.h>

// (B, C2, H, W) = (4, 1024, 64, 64); CH=512, HID=128, P=4096
#define NB 4
#define LOG2E 1.4426950408889634f

typedef unsigned short u16;
typedef __attribute__((ext_vector_type(8))) short bf16x8;
typedef __attribute__((ext_vector_type(4))) float f32x4;

static __device__ __forceinline__ float bf2f(u16 u) {
    union { float f; unsigned v; } x; x.v = ((unsigned)u) << 16; return x.f;
}
static __device__ __forceinline__ u16 f2bf(float f) {
    unsigned v = __builtin_bit_cast(unsigned, f);
    return (u16)((v + 0x7FFFu + ((v >> 16) & 1u)) >> 16);
}

// ---------------- A0: W f32 -> bf16 ----------------
__global__ void k_wcvt(const float* __restrict__ Wq, const float* __restrict__ Wk,
                       u16* __restrict__ Wbq, u16* __restrict__ Wbk) {
    int i = blockIdx.x * 1024 + threadIdx.x;   // 65536
    Wbq[i] = f2bf(Wq[i]);
    Wbk[i] = f2bf(Wk[i]);
}

// ------- A1: f32 -> bf16 convert of first 512 channels; also copy q_orig to out -------
__global__ void k_cvt(const float* __restrict__ L, const float* __restrict__ R,
                      u16* __restrict__ Lb, u16* __restrict__ Rb, float* __restrict__ out) {
    int i = blockIdx.x * 256 + threadIdx.x;     // 4,194,304 float4 granules
    int pq = i & 1023;
    int c = (i >> 10) & 511;
    int b = (i >> 19) & 3;
    int side = i >> 21;
    const float* src = (side ? R : L) + ((long)(b * 1024 + c) << 12) + (pq << 2);
    float4 v = *reinterpret_cast<const float4*>(src);
    ushort4 u;
    u.x = f2bf(v.x); u.y = f2bf(v.y); u.z = f2bf(v.z); u.w = f2bf(v.w);
    *reinterpret_cast<ushort4*>((side ? Rb : Lb) + ((long)(b * 512 + c) << 12) + (pq << 2)) = u;
    *reinterpret_cast<float4*>(out + ((long)(side * 4 + b) * 1024 + c) * 4096 + (pq << 2)) = v;
}

// ---------------- A2: projections via MFMA. Out: pos-major bf16 [p][128] ----------------
__global__ __launch_bounds__(256) void k_proj(
        const u16* __restrict__ Lb, const u16* __restrict__ Rb,
        const u16* __restrict__ Wbq, const u16* __restrict__ Wbk,
        const float* __restrict__ bq, const float* __restrict__ bk,
        u16* __restrict__ QL, u16* __restrict__ KL,
        u16* __restrict__ QR, u16* __restrict__ KR) {
    __shared__ u16 XT[2][64 * 40];
    int pj = blockIdx.x & 15, pt = blockIdx.x >> 4;
    int ty = pj >> 2, b = pj & 3;
    const u16* src; const u16* Wb; const float* bias; u16* dst;
    if (ty == 0)      { src = Lb; Wb = Wbq; bias = bq; dst = QL; }
    else if (ty == 1) { src = Rb; Wb = Wbk; bias = bk; dst = KL; }
    else if (ty == 2) { src = Rb; Wb = Wbq; bias = bq; dst = QR; }
    else              { src = Lb; Wb = Wbk; bias = bk; dst = KR; }
    const u16* X = src + (long)b * 512 * 4096 + pt * 64;
    int tid = threadIdx.x;
    int wv = __builtin_amdgcn_readfirstlane(tid >> 6);
    int lane = tid & 63, g = lane >> 4, li = lane & 15;

    f32x4 acc[8];
#pragma unroll
    for (int ob = 0; ob < 8; ob++)
#pragma unroll
        for (int r = 0; r < 4; r++) acc[ob][r] = bias[ob * 16 + g * 4 + r];

    int c_r = tid >> 3, j = tid & 7;
    bf16x8 gx = *reinterpret_cast<const bf16x8*>(X + (long)c_r * 4096 + j * 8);
#pragma unroll
    for (int k = 0; k < 8; k++) XT[0][(j * 8 + k) * 40 + c_r] = (u16)gx[k];
    __syncthreads();

    for (int cc = 0; cc < 16; cc++) {
        int buf = cc & 1;
        bf16x8 gn;
        if (cc < 15)
            gn = *reinterpret_cast<const bf16x8*>(X + (long)(cc * 32 + 32 + c_r) * 4096 + j * 8);
        bf16x8 xb = *reinterpret_cast<const bf16x8*>(&XT[buf][(wv * 16 + li) * 40 + g * 8]);
#pragma unroll
        for (int ob = 0; ob < 8; ob++) {
            bf16x8 aw = *reinterpret_cast<const bf16x8*>(Wb + (long)(ob * 16 + li) * 512 + cc * 32 + g * 8);
            acc[ob] = __builtin_amdgcn_mfma_f32_16x16x32_bf16(aw, xb, acc[ob], 0, 0, 0);
        }
        if (cc < 15) {
#pragma unroll
            for (int k = 0; k < 8; k++) XT[buf ^ 1][(j * 8 + k) * 40 + c_r] = (u16)gn[k];
        }
        __syncthreads();
    }
    u16* d = dst + ((long)b * 4096 + pt * 64 + wv * 16 + li) * 128;
#pragma unroll
    for (int ob = 0; ob < 8; ob++) {
        uint2 w;
        w.x = (unsigned)f2bf(acc[ob][0]) | ((unsigned)f2bf(acc[ob][1]) << 16);
        w.y = (unsigned)f2bf(acc[ob][2]) | ((unsigned)f2bf(acc[ob][3]) << 16);
        *reinterpret_cast<uint2*>(d + ob * 16 + g * 4) = w;
    }
}

// ---- C: attention. q-tile 128, c-split 2 (block = 128q x 256c), 8 waves.
//      S^T via mfma(K,Q), P through swizzled LDS, PV from global V (L2-resident).
//      Non-draining barrier (lgkmcnt only) keeps K/V prefetches in flight. ----
#define ATTN_BODY(T, KF, KFN, BUF)                                                         \
  {                                                                                        \
    f32x4 sv[2][2];                                                                        \
    _Pragma("unroll") for (int qs = 0; qs < 2; qs++)                                       \
      _Pragma("unroll") for (int pp = 0; pp < 2; pp++)                                     \
        sv[qs][pp] = (f32x4){0.f, 0.f, 0.f, 0.f};                                          \
    __builtin_amdgcn_s_setprio(1);                                                         \
    _Pragma("unroll") for (int hc = 0; hc < 4; hc++)                                       \
      _Pragma("unroll") for (int qs = 0; qs < 2; qs++)                                     \
        _Pragma("unroll") for (int pp = 0; pp < 2; pp++)                                   \
          sv[qs][pp] = __builtin_amdgcn_mfma_f32_16x16x32_bf16(                            \
              KF[pp][hc], qf[qs][hc], sv[qs][pp], 0, 0, 0);                                \
    __builtin_amdgcn_s_setprio(0);                                                         \
    _Pragma("unroll") for (int qs = 0; qs < 2; qs++)                                       \
      _Pragma("unroll") for (int pp = 0; pp < 2; pp++) {                                   \
        float e0 = exp2f(sv[qs][pp][0] * LOG2E);                                           \
        float e1 = exp2f(sv[qs][pp][1] * LOG2E);                                           \
        float e2 = exp2f(sv[qs][pp][2] * LOG2E);                                           \
        float e3 = exp2f(sv[qs][pp][3] * LOG2E);                                           \
        psum[qs] += (e0 + e1) + (e2 + e3);                                                 \
        uint2 pk;                                                                          \
        pk.x = (unsigned)f2bf(e0) | ((unsigned)f2bf(e1) << 16);                            \
        pk.y = (unsigned)f2bf(e2) | ((unsigned)f2bf(e3) << 16);                            \
        unsigned row = (unsigned)(qh * 32 + qs * 16 + li);                                 \
        unsigned off = row * 128u + (((unsigned)(ps * 64 + pp * 32 + g * 8)) ^ swz);       \
        *reinterpret_cast<uint2*>((char*)Plds[BUF] + off) = pk;                            \
      }                                                                                    \
    if ((T) < 63) {                                                                        \
      _Pragma("unroll") for (int pp = 0; pp < 2; pp++)                                     \
        _Pragma("unroll") for (int hc = 0; hc < 4; hc++)                                   \
          KFN[pp][hc] = *reinterpret_cast<const bf16x8*>(                                  \
              Krow + (long)((T) + 1) * 64 * 128 + pp * 16 * 128 + hc * 32);                \
    }                                                                                      \
    asm volatile("s_waitcnt lgkmcnt(0)\n\ts_barrier" ::: "memory");                        \
    bf16x8 pf[4];                                                                          \
    _Pragma("unroll") for (int qs = 0; qs < 4; qs++) {                                     \
      unsigned row = (unsigned)(qh2 * 64 + qs * 16 + li);                                  \
      pf[qs] = *reinterpret_cast<const bf16x8*>(                                           \
          (char*)Plds[BUF] + row * 128u + (((unsigned)(g * 16)) ^ swz));                   \
    }                                                                                      \
    _Pragma("unroll") for (int ct = 0; ct < 4; ct++)                                       \
      vfB[ct] = *reinterpret_cast<const bf16x8*>(Vrow + (long)ct * 16 * 4096 + (T) * 64 + 32); \
    __builtin_amdgcn_s_setprio(1);                                                         \
    _Pragma("unroll") for (int ct = 0; ct < 4; ct++)                                       \
      _Pragma("unroll") for (int qs = 0; qs < 4; qs++)                                     \
        acc[ct][qs] = __builtin_amdgcn_mfma_f32_16x16x32_bf16(vfA[ct], pf[qs], acc[ct][qs], 0, 0, 0); \
    __builtin_amdgcn_s_setprio(0);                                                         \
    _Pragma("unroll") for (int qs = 0; qs < 4; qs++) {                                     \
      unsigned row = (unsigned)(qh2 * 64 + qs * 16 + li);                                  \
      pf[qs] = *reinterpret_cast<const bf16x8*>(                                           \
          (char*)Plds[BUF] + row * 128u + (((unsigned)(64 + g * 16)) ^ swz));              \
    }                                                                                      \
    if ((T) < 63) {                                                                        \
      _Pragma("unroll") for (int ct = 0; ct < 4; ct++)                                     \
        vfA[ct] = *reinterpret_cast<const bf16x8*>(Vrow + (long)ct * 16 * 4096 + ((T) + 1) * 64); \
    }                                                                                      \
    __builtin_amdgcn_s_setprio(1);                                                         \
    _Pragma("unroll") for (int ct = 0; ct < 4; ct++)                                       \
      _Pragma("unroll") for (int qs = 0; qs < 4; qs++)                                     \
        acc[ct][qs] = __builtin_amdgcn_mfma_f32_16x16x32_bf16(vfB[ct], pf[qs], acc[ct][qs], 0, 0, 0); \
    __builtin_amdgcn_s_setprio(0);                                                         \
  }

__global__ __launch_bounds__(512, 2) void k_attn(
        const u16* __restrict__ QL, const u16* __restrict__ KL,
        const u16* __restrict__ QR, const u16* __restrict__ KR,
        const u16* __restrict__ Lb, const u16* __restrict__ Rb,
        float* __restrict__ out) {
    __shared__ u16 Plds[2][128 * 64];    // [q][p] rows 128B, byte^=(li&7)<<4
    __shared__ float sred[2][128];
    int bd = blockIdx.x & 7;             // (b,dir) -> XCD pin
    int cs = (blockIdx.x >> 3) & 1;      // channel half
    int qb = blockIdx.x >> 4;            // 0..31
    int dir = bd & 1, b = bd >> 1;
    const u16* Qt = (dir ? QR : QL) + (long)b * 4096 * 128;
    const u16* Kt = (dir ? KR : KL) + (long)b * 4096 * 128;
    const u16* V  = (dir ? Lb : Rb) + (long)b * 512 * 4096 + (long)cs * 256 * 4096;
    float* o = out + (long)(dir * 4 + b) * 1024 * 4096 + (long)(512 + cs * 256) * 4096;
    int q0 = qb * 128;
    int wv = __builtin_amdgcn_readfirstlane(threadIdx.x >> 6);
    int lane = threadIdx.x & 63, g = lane >> 4, li = lane & 15;
    // S-phase roles: 4 q-groups x 2 p-halves; PV roles: 4 c-slices x 2 q-halves
    int qh = wv >> 1, ps = wv & 1;
    int cQ = wv >> 1, qh2 = wv & 1;
    const unsigned swz = ((unsigned)(li & 7)) << 4;

    bf16x8 qf[2][4];
#pragma unroll
    for (int qs = 0; qs < 2; qs++)
#pragma unroll
        for (int hc = 0; hc < 4; hc++)
            qf[qs][hc] = *reinterpret_cast<const bf16x8*>(
                Qt + (long)(q0 + qh * 32 + qs * 16 + li) * 128 + hc * 32 + g * 8);

    f32x4 acc[4][4];
#pragma unroll
    for (int i = 0; i < 4; i++)
#pragma unroll
        for (int j = 0; j < 4; j++) acc[i][j] = (f32x4){0.f, 0.f, 0.f, 0.f};
    float psum[2] = {0.f, 0.f};

    const u16* Krow = Kt + (long)(ps * 32 + li) * 128 + g * 8;
    const u16* Vrow = V + (long)(cQ * 64 + li) * 4096 + g * 8;

    bf16x8 kfA[2][4], kfB[2][4], vfA[4], vfB[4];
#pragma unroll
    for (int pp = 0; pp < 2; pp++)
#pragma unroll
        for (int hc = 0; hc < 4; hc++)
            kfA[pp][hc] = *reinterpret_cast<const bf16x8*>(Krow + pp * 16 * 128 + hc * 32);
#pragma unroll
    for (int ct = 0; ct < 4; ct++)
        vfA[ct] = *reinterpret_cast<const bf16x8*>(Vrow + (long)ct * 16 * 4096);

    for (int t = 0; t < 64; t += 2) {
        ATTN_BODY(t,     kfA, kfB, 0)
        ATTN_BODY(t + 1, kfB, kfA, 1)
    }

    // row-sum reduce: over g (shfl), then across ps via LDS
#pragma unroll
    for (int qs = 0; qs < 2; qs++) {
        float p = psum[qs];
        p += __shfl_xor(p, 16);
        p += __shfl_xor(p, 32);
        if (lane < 16) sred[ps][qh * 32 + qs * 16 + li] = p;
    }
    __syncthreads();
#pragma unroll
    for (int qs = 0; qs < 4; qs++) {
        int qr = qh2 * 64 + qs * 16 + li;
        float linv = 1.0f / (sred[0][qr] + sred[1][qr]);
#pragma unroll
        for (int ct = 0; ct < 4; ct++)
#pragma unroll
            for (int r = 0; r < 4; r++)
                o[(long)(cQ * 64 + ct * 16 + g * 4 + r) * 4096 + q0 + qr] =
                    acc[ct][qs][r] * linv;
    }
}

// ---------------- D: homo softmax term (no max pass; exp cached in LDS bf16) ----------------
__global__ __launch_bounds__(256) void k_homo(const float* __restrict__ L,
                                              const float* __restrict__ R,
                                              float* __restrict__ out) {
    __shared__ u16 elds[512][64];   // 64KB
    __shared__ float red[4][64];
    int sb = blockIdx.x & 7, pc = blockIdx.x >> 3;
    int side = sb & 1, b = sb >> 1;
    const float* src = (side ? R : L) + (long)b * 1024 * 4096;
    float* o = out + (long)(side * 4 + b) * 1024 * 4096;
    int p_l = threadIdx.x & 63, cg = threadIdx.x >> 6;
    int p = pc * 64 + p_l;
    const float* qo = src + p;
    const float* qt = src + (long)512 * 4096 + p;
    float sm = 0.f;
    for (int c = cg * 128; c < cg * 128 + 128; c++) {
        float a = qo[(long)c * 4096], t = qt[(long)c * 4096];
        float e = exp2f((a - t) * LOG2E);
        elds[c][p_l] = f2bf(e);
        sm += e;
    }
    red[cg][p_l] = sm;
    __syncthreads();
    float rinv = 1.0f / (red[0][p_l] + red[1][p_l] + red[2][p_l] + red[3][p_l]);
    for (int c = cg * 128; c < cg * 128 + 128; c++) {
        float t = qt[(long)c * 4096];
        float w = bf2f(elds[c][p_l]) * rinv;
        long oi = (long)(512 + c) * 4096 + p;
        o[oi] = o[oi] + t * w;
    }
}

extern "C" void kernel_launch(void* const* d_in, const int* in_sizes, int n_in,
                              void* d_out, int out_size, void* d_ws, size_t ws_size,
                              hipStream_t stream) {
    const float* L  = (const float*)d_in[0];
    const float* R  = (const float*)d_in[1];
    const float* Wq = (const float*)d_in[2];
    const float* bq = (const float*)d_in[3];
    const float* Wk = (const float*)d_in[4];
    const float* bk = (const float*)d_in[5];
    float* out = (float*)d_out;
    char* ws = (char*)d_ws;

    size_t off = 0;
    u16* Wbq = (u16*)(ws + off); off += (size_t)128 * 512 * 2;
    u16* Wbk = (u16*)(ws + off); off += (size_t)128 * 512 * 2;
    u16* QL = (u16*)(ws + off); off += (size_t)NB * 4096 * 128 * 2;
    u16* KL = (u16*)(ws + off); off += (size_t)NB * 4096 * 128 * 2;
    u16* QR = (u16*)(ws + off); off += (size_t)NB * 4096 * 128 * 2;
    u16* KR = (u16*)(ws + off); off += (size_t)NB * 4096 * 128 * 2;
    u16* Lb = (u16*)(ws + off); off += (size_t)NB * 512 * 4096 * 2;
    u16* Rb = (u16*)(ws + off); off += (size_t)NB * 512 * 4096 * 2;

    k_wcvt <<<64,    1024, 0, stream>>>(Wq, Wk, Wbq, Wbk);
    k_cvt  <<<16384, 256,  0, stream>>>(L, R, Lb, Rb, out);
    k_proj <<<1024,  256,  0, stream>>>(Lb, Rb, Wbq, Wbk, bq, bk, QL, KL, QR, KR);
    k_attn <<<512,   512,  0, stream>>>(QL, KL, QR, KR, Lb, Rb, out);
    k_homo <<<512,   256,  0, stream>>>(L, R, out);
}

// Round 4
// 482.550 us; speedup vs baseline: 1.5837x; 1.5837x over previous
//
#include <hip/hip_runtime.h>
#include <hip/hip_bf16.h>

// (B, C2, H, W) = (4, 1024, 64, 64); CH=512, HID=128, P=4096
#define NB 4
#define LOG2E 1.4426950408889634f

typedef unsigned short u16;
typedef __attribute__((ext_vector_type(8))) short bf16x8;
typedef __attribute__((ext_vector_type(4))) float f32x4;

static __device__ __forceinline__ float bf2f(u16 u) {
    union { float f; unsigned v; } x; x.v = ((unsigned)u) << 16; return x.f;
}
static __device__ __forceinline__ u16 f2bf(float f) {
    unsigned v = __builtin_bit_cast(unsigned, f);
    return (u16)((v + 0x7FFFu + ((v >> 16) & 1u)) >> 16);
}
static __device__ __forceinline__ void gload_lds16(const u16* g, u16* l) {
    __builtin_amdgcn_global_load_lds(
        (const __attribute__((address_space(1))) unsigned*)(const void*)g,
        (__attribute__((address_space(3))) unsigned*)(void*)l, 16, 0, 0);
}

// ---------------- A0: W f32 -> bf16 ----------------
__global__ void k_wcvt(const float* __restrict__ Wq, const float* __restrict__ Wk,
                       u16* __restrict__ Wbq, u16* __restrict__ Wbk) {
    int i = blockIdx.x * 1024 + threadIdx.x;   // 65536
    Wbq[i] = f2bf(Wq[i]);
    Wbk[i] = f2bf(Wk[i]);
}

// ------- A1: f32 -> bf16 convert of first 512 channels; also copy q_orig to out -------
__global__ void k_cvt(const float* __restrict__ L, const float* __restrict__ R,
                      u16* __restrict__ Lb, u16* __restrict__ Rb, float* __restrict__ out) {
    int i = blockIdx.x * 256 + threadIdx.x;     // 4,194,304 float4 granules
    int pq = i & 1023;
    int c = (i >> 10) & 511;
    int b = (i >> 19) & 3;
    int side = i >> 21;
    const float* src = (side ? R : L) + ((long)(b * 1024 + c) << 12) + (pq << 2);
    float4 v = *reinterpret_cast<const float4*>(src);
    ushort4 u;
    u.x = f2bf(v.x); u.y = f2bf(v.y); u.z = f2bf(v.z); u.w = f2bf(v.w);
    *reinterpret_cast<ushort4*>((side ? Rb : Lb) + ((long)(b * 512 + c) << 12) + (pq << 2)) = u;
    *reinterpret_cast<float4*>(out + ((long)(side * 4 + b) * 1024 + c) * 4096 + (pq << 2)) = v;
}

// ---------------- A2: projections via MFMA. Out: pos-major bf16 [p][128] ----------------
__global__ __launch_bounds__(256) void k_proj(
        const u16* __restrict__ Lb, const u16* __restrict__ Rb,
        const u16* __restrict__ Wbq, const u16* __restrict__ Wbk,
        const float* __restrict__ bq, const float* __restrict__ bk,
        u16* __restrict__ QL, u16* __restrict__ KL,
        u16* __restrict__ QR, u16* __restrict__ KR) {
    __shared__ u16 XT[2][64 * 40];
    int pj = blockIdx.x & 15, pt = blockIdx.x >> 4;
    int ty = pj >> 2, b = pj & 3;
    const u16* src; const u16* Wb; const float* bias; u16* dst;
    if (ty == 0)      { src = Lb; Wb = Wbq; bias = bq; dst = QL; }
    else if (ty == 1) { src = Rb; Wb = Wbk; bias = bk; dst = KL; }
    else if (ty == 2) { src = Rb; Wb = Wbq; bias = bq; dst = QR; }
    else              { src = Lb; Wb = Wbk; bias = bk; dst = KR; }
    const u16* X = src + (long)b * 512 * 4096 + pt * 64;
    int tid = threadIdx.x;
    int wv = __builtin_amdgcn_readfirstlane(tid >> 6);
    int lane = tid & 63, g = lane >> 4, li = lane & 15;

    f32x4 acc[8];
#pragma unroll
    for (int ob = 0; ob < 8; ob++)
#pragma unroll
        for (int r = 0; r < 4; r++) acc[ob][r] = bias[ob * 16 + g * 4 + r];

    int c_r = tid >> 3, j = tid & 7;
    bf16x8 gx = *reinterpret_cast<const bf16x8*>(X + (long)c_r * 4096 + j * 8);
#pragma unroll
    for (int k = 0; k < 8; k++) XT[0][(j * 8 + k) * 40 + c_r] = (u16)gx[k];
    __syncthreads();

    for (int cc = 0; cc < 16; cc++) {
        int buf = cc & 1;
        bf16x8 gn;
        if (cc < 15)
            gn = *reinterpret_cast<const bf16x8*>(X + (long)(cc * 32 + 32 + c_r) * 4096 + j * 8);
        bf16x8 xb = *reinterpret_cast<const bf16x8*>(&XT[buf][(wv * 16 + li) * 40 + g * 8]);
#pragma unroll
        for (int ob = 0; ob < 8; ob++) {
            bf16x8 aw = *reinterpret_cast<const bf16x8*>(Wb + (long)(ob * 16 + li) * 512 + cc * 32 + g * 8);
            acc[ob] = __builtin_amdgcn_mfma_f32_16x16x32_bf16(aw, xb, acc[ob], 0, 0, 0);
        }
        if (cc < 15) {
#pragma unroll
            for (int k = 0; k < 8; k++) XT[buf ^ 1][(j * 8 + k) * 40 + c_r] = (u16)gn[k];
        }
        __syncthreads();
    }
    u16* d = dst + ((long)b * 4096 + pt * 64 + wv * 16 + li) * 128;
#pragma unroll
    for (int ob = 0; ob < 8; ob++) {
        uint2 w;
        w.x = (unsigned)f2bf(acc[ob][0]) | ((unsigned)f2bf(acc[ob][1]) << 16);
        w.y = (unsigned)f2bf(acc[ob][2]) | ((unsigned)f2bf(acc[ob][3]) << 16);
        *reinterpret_cast<uint2*>(d + ob * 16 + g * 4) = w;
    }
}

// ---- B1: P = exp(Q.K^T) (bf16, [q][p] row-major) + row-sum reciprocals ----
// block 512 thr (8 waves: qt=wv>>1 q-subtile, ph=wv&1 p-half); q-tile 64, p-step 64.
__global__ __launch_bounds__(512) void k_qk(
        const u16* __restrict__ QL, const u16* __restrict__ KL,
        const u16* __restrict__ QR, const u16* __restrict__ KR,
        u16* __restrict__ P, float* __restrict__ linvArr,
        int bd0, int bdMask, int bdShift) {
    __shared__ u16 Kl[2][8192];       // [64p][128c] 16KB each, byte^=(p&7)<<4
    __shared__ u16 Ps[4096];          // [64q][64p] 8KB, byte^=(q&7)<<4
    __shared__ float sred[4][2][16];
    int bdl = (int)blockIdx.x & bdMask;
    int qtile = (int)blockIdx.x >> bdShift;
    int bd = bd0 + bdl, dir = bd & 1, b = bd >> 1;
    const u16* Qt = (dir ? QR : QL) + (size_t)b * 4096 * 128;
    const u16* Kt = (dir ? KR : KL) + (size_t)b * 4096 * 128;
    u16* Pbd = P + ((size_t)bdl << 24);
    int q0 = qtile * 64;
    int tid = threadIdx.x;
    int wv = __builtin_amdgcn_readfirstlane(tid >> 6);
    int lane = tid & 63, g = lane >> 4, li = lane & 15;
    int qt = wv >> 1, ph = wv & 1;

#define STAGE_K(BUF, P0)                                                                   \
    {                                                                                      \
        _Pragma("unroll") for (int r0 = 0; r0 < 2; r0++) {                                 \
            int o = r0 * 8192 + tid * 16;                                                  \
            int row = o >> 8, w = o & 255;                                                 \
            int sw = (w ^ ((row & 7) << 4)) >> 1;                                          \
            gload_lds16(Kt + (((size_t)((P0) + row)) << 7) + sw,                           \
                        &Kl[BUF][r0 * 4096 + wv * 512]);                                   \
        }                                                                                  \
    }

    bf16x8 qf[4];
#pragma unroll
    for (int hc = 0; hc < 4; hc++)
        qf[hc] = *reinterpret_cast<const bf16x8*>(
            Qt + (size_t)(q0 + qt * 16 + li) * 128 + hc * 32 + g * 8);
    float psum = 0.f;
    STAGE_K(0, 0)

    for (int t = 0; t < 64; t++) {
        if (t == 0) asm volatile("s_waitcnt vmcnt(0) lgkmcnt(0)\n\ts_barrier" ::: "memory");
        else        asm volatile("s_waitcnt vmcnt(1) lgkmcnt(0)\n\ts_barrier" ::: "memory");
        if (t < 63) STAGE_K((t + 1) & 1, (t + 1) * 64)
        int buf = t & 1;
        f32x4 sv[2];
        sv[0] = (f32x4){0.f, 0.f, 0.f, 0.f};
        sv[1] = (f32x4){0.f, 0.f, 0.f, 0.f};
        __builtin_amdgcn_s_setprio(1);
#pragma unroll
        for (int ps = 0; ps < 2; ps++) {
            int row = ph * 32 + ps * 16 + li;
            unsigned rb = (unsigned)row * 256;
            unsigned sz = (unsigned)((row & 7) << 4);
#pragma unroll
            for (int hc = 0; hc < 4; hc++) {
                bf16x8 kf = *reinterpret_cast<const bf16x8*>(
                    (char*)Kl[buf] + rb + (((unsigned)(hc * 64 + g * 16)) ^ sz));
                sv[ps] = __builtin_amdgcn_mfma_f32_16x16x32_bf16(kf, qf[hc], sv[ps], 0, 0, 0);
            }
        }
        __builtin_amdgcn_s_setprio(0);
        int qrow = qt * 16 + li;
        unsigned qsz = (unsigned)((qrow & 7) << 4);
#pragma unroll
        for (int ps = 0; ps < 2; ps++) {
            float e0 = exp2f(sv[ps][0] * LOG2E);
            float e1 = exp2f(sv[ps][1] * LOG2E);
            float e2 = exp2f(sv[ps][2] * LOG2E);
            float e3 = exp2f(sv[ps][3] * LOG2E);
            psum += (e0 + e1) + (e2 + e3);
            uint2 pk;
            pk.x = (unsigned)f2bf(e0) | ((unsigned)f2bf(e1) << 16);
            pk.y = (unsigned)f2bf(e2) | ((unsigned)f2bf(e3) << 16);
            unsigned off = (unsigned)qrow * 128 +
                           (((unsigned)(ph * 64 + ps * 32 + g * 8)) ^ qsz);
            *reinterpret_cast<uint2*>((char*)Ps + off) = pk;
        }
        asm volatile("s_waitcnt lgkmcnt(0)\n\ts_barrier" ::: "memory");
        {
            int row = tid >> 3, w = (tid & 7) * 16;
            uint4 d = *reinterpret_cast<const uint4*>(
                (char*)Ps + row * 128 + (w ^ ((row & 7) << 4)));
            *reinterpret_cast<uint4*>(Pbd + (((size_t)(q0 + row)) << 12) + t * 64 + (w >> 1)) = d;
        }
    }
    psum += __shfl_xor(psum, 16);
    psum += __shfl_xor(psum, 32);
    if (lane < 16) sred[qt][ph][li] = psum;
    __syncthreads();
    if (ph == 0 && lane < 16) {
        float s = sred[qt][0][li] + sred[qt][1][li];
        linvArr[(size_t)bd * 4096 + q0 + qt * 16 + li] = 1.0f / s;
    }
#undef STAGE_K
}

// ---- B2: O[c][q] = (V . P^T) * linv[q]  — m97-style 128x128 GEMM, BK=64, dbuf LDS ----
__global__ __launch_bounds__(256) void k_pv(
        const u16* __restrict__ Lb, const u16* __restrict__ Rb,
        const u16* __restrict__ P, const float* __restrict__ linvArr,
        float* __restrict__ out, int bd0, int bdMask, int bdShift) {
    __shared__ u16 Tl[2][2][8192];     // [buf][A=V/B=P][128 rows][64 k] 16KB each
    int bdl = (int)blockIdx.x & bdMask;
    int idx = (int)blockIdx.x >> bdShift;
    int mtile = idx & 3;               // 4 x 128 channels
    int ntile = idx >> 2;              // 32 x 128 q
    int bd = bd0 + bdl, dir = bd & 1, b = bd >> 1;
    const u16* V = (dir ? Lb : Rb) + (size_t)b * 512 * 4096;
    const u16* Pbd = P + ((size_t)bdl << 24);
    int q0 = ntile * 128, c0 = mtile * 128;
    int tid = threadIdx.x;
    int wv = __builtin_amdgcn_readfirstlane(tid >> 6);
    int lane = tid & 63, g = lane >> 4, li = lane & 15;
    int wr = wv >> 1, wc = wv & 1;     // wave tile: 64c x 64q

#define STAGE_PV(BUF, P0)                                                                  \
    {                                                                                      \
        _Pragma("unroll") for (int r0 = 0; r0 < 4; r0++) {                                 \
            int o = r0 * 4096 + tid * 16;                                                  \
            int row = o >> 7, w = o & 127;                                                 \
            int sw = (w ^ ((row & 7) << 4)) >> 1;                                          \
            gload_lds16(V + (((size_t)(c0 + row)) << 12) + (P0) + sw,                      \
                        &Tl[BUF][0][r0 * 2048 + wv * 512]);                                \
            gload_lds16(Pbd + (((size_t)(q0 + row)) << 12) + (P0) + sw,                    \
                        &Tl[BUF][1][r0 * 2048 + wv * 512]);                                \
        }                                                                                  \
    }

    f32x4 acc[4][4];
#pragma unroll
    for (int i = 0; i < 4; i++)
#pragma unroll
        for (int j = 0; j < 4; j++) acc[i][j] = (f32x4){0.f, 0.f, 0.f, 0.f};

    STAGE_PV(0, 0)

    for (int t = 0; t < 64; t++) {
        asm volatile("s_waitcnt vmcnt(0) lgkmcnt(0)\n\ts_barrier" ::: "memory");
        if (t < 63) STAGE_PV((t + 1) & 1, (t + 1) * 64)
        int buf = t & 1;
        bf16x8 af[4][2], bf[4][2];
#pragma unroll
        for (int mi = 0; mi < 4; mi++) {
            int row = wr * 64 + mi * 16 + li;
            unsigned rb = (unsigned)row * 128, sz = (unsigned)((row & 7) << 4);
#pragma unroll
            for (int kk = 0; kk < 2; kk++)
                af[mi][kk] = *reinterpret_cast<const bf16x8*>(
                    (char*)Tl[buf][0] + rb + (((unsigned)(kk * 64 + g * 16)) ^ sz));
        }
#pragma unroll
        for (int ni = 0; ni < 4; ni++) {
            int row = wc * 64 + ni * 16 + li;
            unsigned rb = (unsigned)row * 128, sz = (unsigned)((row & 7) << 4);
#pragma unroll
            for (int kk = 0; kk < 2; kk++)
                bf[ni][kk] = *reinterpret_cast<const bf16x8*>(
                    (char*)Tl[buf][1] + rb + (((unsigned)(kk * 64 + g * 16)) ^ sz));
        }
        __builtin_amdgcn_s_setprio(1);
#pragma unroll
        for (int kk = 0; kk < 2; kk++)
#pragma unroll
            for (int mi = 0; mi < 4; mi++)
#pragma unroll
                for (int ni = 0; ni < 4; ni++)
                    acc[mi][ni] = __builtin_amdgcn_mfma_f32_16x16x32_bf16(
                        af[mi][kk], bf[ni][kk], acc[mi][ni], 0, 0, 0);
        __builtin_amdgcn_s_setprio(0);
    }

    float* obase = out + ((size_t)(dir * 4 + b) * 1024 + 512) * 4096;
#pragma unroll
    for (int ni = 0; ni < 4; ni++) {
        int q = q0 + wc * 64 + ni * 16 + li;
        float linv = linvArr[(size_t)bd * 4096 + q];
#pragma unroll
        for (int mi = 0; mi < 4; mi++) {
            int c = c0 + wr * 64 + mi * 16 + g * 4;
#pragma unroll
            for (int r = 0; r < 4; r++)
                obase[(size_t)(c + r) * 4096 + q] = acc[mi][ni][r] * linv;
        }
    }
#undef STAGE_PV
}

// ---------------- D: homo softmax term (no max pass; exp cached in LDS bf16) ----------------
__global__ __launch_bounds__(256) void k_homo(const float* __restrict__ L,
                                              const float* __restrict__ R,
                                              float* __restrict__ out) {
    __shared__ u16 elds[512][64];   // 64KB
    __shared__ float red[4][64];
    int sb = blockIdx.x & 7, pc = blockIdx.x >> 3;
    int side = sb & 1, b = sb >> 1;
    const float* src = (side ? R : L) + (long)b * 1024 * 4096;
    float* o = out + (long)(side * 4 + b) * 1024 * 4096;
    int p_l = threadIdx.x & 63, cg = threadIdx.x >> 6;
    int p = pc * 64 + p_l;
    const float* qo = src + p;
    const float* qt = src + (long)512 * 4096 + p;
    float sm = 0.f;
    for (int c = cg * 128; c < cg * 128 + 128; c++) {
        float a = qo[(long)c * 4096], t = qt[(long)c * 4096];
        float e = exp2f((a - t) * LOG2E);
        elds[c][p_l] = f2bf(e);
        sm += e;
    }
    red[cg][p_l] = sm;
    __syncthreads();
    float rinv = 1.0f / (red[0][p_l] + red[1][p_l] + red[2][p_l] + red[3][p_l]);
    for (int c = cg * 128; c < cg * 128 + 128; c++) {
        float t = qt[(long)c * 4096];
        float w = bf2f(elds[c][p_l]) * rinv;
        long oi = (long)(512 + c) * 4096 + p;
        o[oi] = o[oi] + t * w;
    }
}

extern "C" void kernel_launch(void* const* d_in, const int* in_sizes, int n_in,
                              void* d_out, int out_size, void* d_ws, size_t ws_size,
                              hipStream_t stream) {
    const float* L  = (const float*)d_in[0];
    const float* R  = (const float*)d_in[1];
    const float* Wq = (const float*)d_in[2];
    const float* bq = (const float*)d_in[3];
    const float* Wk = (const float*)d_in[4];
    const float* bk = (const float*)d_in[5];
    float* out = (float*)d_out;
    char* ws = (char*)d_ws;

    size_t off = 0;
    u16* Wbq = (u16*)(ws + off); off += (size_t)128 * 512 * 2;
    u16* Wbk = (u16*)(ws + off); off += (size_t)128 * 512 * 2;
    u16* QL = (u16*)(ws + off); off += (size_t)NB * 4096 * 128 * 2;
    u16* KL = (u16*)(ws + off); off += (size_t)NB * 4096 * 128 * 2;
    u16* QR = (u16*)(ws + off); off += (size_t)NB * 4096 * 128 * 2;
    u16* KR = (u16*)(ws + off); off += (size_t)NB * 4096 * 128 * 2;
    u16* Lb = (u16*)(ws + off); off += (size_t)NB * 512 * 4096 * 2;
    u16* Rb = (u16*)(ws + off); off += (size_t)NB * 512 * 4096 * 2;
    float* linv = (float*)(ws + off); off += (size_t)8 * 4096 * 4;
    off = (off + 255) & ~(size_t)255;
    u16* Pb = (u16*)(ws + off);

    // chunking: prefer 4 bd per chunk (P chunk = 128MB, L3-resident); fallback 1 bd.
    size_t pchunk4 = (size_t)4 * 4096 * 4096 * 2;
    int nbd, bdShift;
    if (ws_size >= off + pchunk4) { nbd = 4; bdShift = 2; }
    else                          { nbd = 1; bdShift = 0; }
    int bdMask = nbd - 1;
    int nchunk = 8 / nbd;

    k_wcvt <<<64,    1024, 0, stream>>>(Wq, Wk, Wbq, Wbk);
    k_cvt  <<<16384, 256,  0, stream>>>(L, R, Lb, Rb, out);
    k_proj <<<1024,  256,  0, stream>>>(Lb, Rb, Wbq, Wbk, bq, bk, QL, KL, QR, KR);
    for (int c = 0; c < nchunk; c++) {
        k_qk <<<nbd * 64,  512, 0, stream>>>(QL, KL, QR, KR, Pb, linv,
                                             c * nbd, bdMask, bdShift);
        k_pv <<<nbd * 128, 256, 0, stream>>>(Lb, Rb, Pb, linv, out,
                                             c * nbd, bdMask, bdShift);
    }
    k_homo <<<512,   256,  0, stream>>>(L, R, out);
}

// Round 5
// 418.522 us; speedup vs baseline: 1.8260x; 1.1530x over previous
//
#include <hip/hip_runtime.h>
#include <hip/hip_bf16.h>

// (B, C2, H, W) = (4, 1024, 64, 64); CH=512, HID=128, P=4096
#define NB 4
#define LOG2E 1.4426950408889634f

typedef unsigned short u16;
typedef __attribute__((ext_vector_type(8))) short bf16x8;
typedef __attribute__((ext_vector_type(4))) float f32x4;

static __device__ __forceinline__ float bf2f(u16 u) {
    union { float f; unsigned v; } x; x.v = ((unsigned)u) << 16; return x.f;
}
static __device__ __forceinline__ u16 f2bf(float f) {
    unsigned v = __builtin_bit_cast(unsigned, f);
    return (u16)((v + 0x7FFFu + ((v >> 16) & 1u)) >> 16);
}
static __device__ __forceinline__ void gload_lds16(const u16* g, u16* l) {
    __builtin_amdgcn_global_load_lds(
        (const __attribute__((address_space(1))) unsigned*)(const void*)g,
        (__attribute__((address_space(3))) unsigned*)(void*)l, 16, 0, 0);
}

// ---------------- A0: W f32 -> bf16 ----------------
__global__ void k_wcvt(const float* __restrict__ Wq, const float* __restrict__ Wk,
                       u16* __restrict__ Wbq, u16* __restrict__ Wbk) {
    int i = blockIdx.x * 1024 + threadIdx.x;   // 65536
    Wbq[i] = f2bf(Wq[i]);
    Wbk[i] = f2bf(Wk[i]);
}

// ------- A1: f32 -> bf16 convert of first 512 channels; also copy q_orig to out -------
__global__ void k_cvt(const float* __restrict__ L, const float* __restrict__ R,
                      u16* __restrict__ Lb, u16* __restrict__ Rb, float* __restrict__ out) {
    int i = blockIdx.x * 256 + threadIdx.x;     // 4,194,304 float4 granules
    int pq = i & 1023;
    int c = (i >> 10) & 511;
    int b = (i >> 19) & 3;
    int side = i >> 21;
    const float* src = (side ? R : L) + ((long)(b * 1024 + c) << 12) + (pq << 2);
    float4 v = *reinterpret_cast<const float4*>(src);
    ushort4 u;
    u.x = f2bf(v.x); u.y = f2bf(v.y); u.z = f2bf(v.z); u.w = f2bf(v.w);
    *reinterpret_cast<ushort4*>((side ? Rb : Lb) + ((long)(b * 512 + c) << 12) + (pq << 2)) = u;
    *reinterpret_cast<float4*>(out + ((long)(side * 4 + b) * 1024 + c) * 4096 + (pq << 2)) = v;
}

// ---------------- A2: projections via MFMA. Out: pos-major bf16 [p][128] ----------------
__global__ __launch_bounds__(256) void k_proj(
        const u16* __restrict__ Lb, const u16* __restrict__ Rb,
        const u16* __restrict__ Wbq, const u16* __restrict__ Wbk,
        const float* __restrict__ bq, const float* __restrict__ bk,
        u16* __restrict__ QL, u16* __restrict__ KL,
        u16* __restrict__ QR, u16* __restrict__ KR) {
    __shared__ u16 XT[2][64 * 40];
    int pj = blockIdx.x & 15, pt = blockIdx.x >> 4;
    int ty = pj >> 2, b = pj & 3;
    const u16* src; const u16* Wb; const float* bias; u16* dst;
    if (ty == 0)      { src = Lb; Wb = Wbq; bias = bq; dst = QL; }
    else if (ty == 1) { src = Rb; Wb = Wbk; bias = bk; dst = KL; }
    else if (ty == 2) { src = Rb; Wb = Wbq; bias = bq; dst = QR; }
    else              { src = Lb; Wb = Wbk; bias = bk; dst = KR; }
    const u16* X = src + (long)b * 512 * 4096 + pt * 64;
    int tid = threadIdx.x;
    int wv = __builtin_amdgcn_readfirstlane(tid >> 6);
    int lane = tid & 63, g = lane >> 4, li = lane & 15;

    f32x4 acc[8];
#pragma unroll
    for (int ob = 0; ob < 8; ob++)
#pragma unroll
        for (int r = 0; r < 4; r++) acc[ob][r] = bias[ob * 16 + g * 4 + r];

    int c_r = tid >> 3, j = tid & 7;
    bf16x8 gx = *reinterpret_cast<const bf16x8*>(X + (long)c_r * 4096 + j * 8);
#pragma unroll
    for (int k = 0; k < 8; k++) XT[0][(j * 8 + k) * 40 + c_r] = (u16)gx[k];
    __syncthreads();

    for (int cc = 0; cc < 16; cc++) {
        int buf = cc & 1;
        bf16x8 gn;
        if (cc < 15)
            gn = *reinterpret_cast<const bf16x8*>(X + (long)(cc * 32 + 32 + c_r) * 4096 + j * 8);
        bf16x8 xb = *reinterpret_cast<const bf16x8*>(&XT[buf][(wv * 16 + li) * 40 + g * 8]);
#pragma unroll
        for (int ob = 0; ob < 8; ob++) {
            bf16x8 aw = *reinterpret_cast<const bf16x8*>(Wb + (long)(ob * 16 + li) * 512 + cc * 32 + g * 8);
            acc[ob] = __builtin_amdgcn_mfma_f32_16x16x32_bf16(aw, xb, acc[ob], 0, 0, 0);
        }
        if (cc < 15) {
#pragma unroll
            for (int k = 0; k < 8; k++) XT[buf ^ 1][(j * 8 + k) * 40 + c_r] = (u16)gn[k];
        }
        __syncthreads();
    }
    u16* d = dst + ((long)b * 4096 + pt * 64 + wv * 16 + li) * 128;
#pragma unroll
    for (int ob = 0; ob < 8; ob++) {
        uint2 w;
        w.x = (unsigned)f2bf(acc[ob][0]) | ((unsigned)f2bf(acc[ob][1]) << 16);
        w.y = (unsigned)f2bf(acc[ob][2]) | ((unsigned)f2bf(acc[ob][3]) << 16);
        *reinterpret_cast<uint2*>(d + ob * 16 + g * 4) = w;
    }
}

// ---- B1: P = exp(Q.K^T), written as 8KB tiles [qtile][ptile][64q][64p] (swizzle baked).
//      p-split x2 across blocks; partial row-sums -> sums[ph0][bd][q]. ----
__global__ __launch_bounds__(512, 4) void k_qk(
        const u16* __restrict__ QL, const u16* __restrict__ KL,
        const u16* __restrict__ QR, const u16* __restrict__ KR,
        u16* __restrict__ P, float* __restrict__ sums,
        int bd0, int bdMask, int bdShift) {
    __shared__ u16 Kl[2][8192];       // [64p][128c] 16KB each, byte^=(p&7)<<4
    __shared__ u16 Ps[4096];          // [64q][64p] 8KB, byte^=(q&7)<<4
    __shared__ float sred[4][2][16];
    int bdl = (int)blockIdx.x & bdMask;
    int rest = (int)blockIdx.x >> bdShift;
    int qtile = rest & 63;
    int ph0 = rest >> 6;              // p-half: tiles [ph0*32, ph0*32+32)
    int bd = bd0 + bdl, dir = bd & 1, b = bd >> 1;
    const u16* Qt = (dir ? QR : QL) + (size_t)b * 4096 * 128;
    const u16* Kt = (dir ? KR : KL) + (size_t)b * 4096 * 128;
    u16* Pbd = P + ((size_t)bdl << 24);
    int q0 = qtile * 64;
    int tid = threadIdx.x;
    int wv = __builtin_amdgcn_readfirstlane(tid >> 6);
    int lane = tid & 63, g = lane >> 4, li = lane & 15;
    int qt = wv >> 1, phw = wv & 1;

#define STAGE_K(BUF, PT)                                                                   \
    {                                                                                      \
        _Pragma("unroll") for (int r0 = 0; r0 < 2; r0++) {                                 \
            int o = r0 * 8192 + tid * 16;                                                  \
            int row = o >> 8, w = o & 255;                                                 \
            int sw = (w ^ ((row & 7) << 4)) >> 1;                                          \
            gload_lds16(Kt + (((size_t)((PT) * 64 + row)) << 7) + sw,                      \
                        &Kl[BUF][r0 * 4096 + wv * 512]);                                   \
        }                                                                                  \
    }

    bf16x8 qf[4];
#pragma unroll
    for (int hc = 0; hc < 4; hc++)
        qf[hc] = *reinterpret_cast<const bf16x8*>(
            Qt + (size_t)(q0 + qt * 16 + li) * 128 + hc * 32 + g * 8);
    float psum = 0.f;
    STAGE_K(0, ph0 * 32)

    for (int tt = 0; tt < 32; tt++) {
        int pt = ph0 * 32 + tt;
        if (tt == 0) asm volatile("s_waitcnt vmcnt(0) lgkmcnt(0)\n\ts_barrier" ::: "memory");
        else         asm volatile("s_waitcnt vmcnt(1) lgkmcnt(0)\n\ts_barrier" ::: "memory");
        if (tt < 31) STAGE_K((tt + 1) & 1, pt + 1)
        int buf = tt & 1;
        f32x4 sv[2];
        sv[0] = (f32x4){0.f, 0.f, 0.f, 0.f};
        sv[1] = (f32x4){0.f, 0.f, 0.f, 0.f};
        __builtin_amdgcn_s_setprio(1);
#pragma unroll
        for (int ps = 0; ps < 2; ps++) {
            int row = phw * 32 + ps * 16 + li;
            unsigned rb = (unsigned)row * 256;
            unsigned sz = (unsigned)((row & 7) << 4);
#pragma unroll
            for (int hc = 0; hc < 4; hc++) {
                bf16x8 kf = *reinterpret_cast<const bf16x8*>(
                    (char*)Kl[buf] + rb + (((unsigned)(hc * 64 + g * 16)) ^ sz));
                sv[ps] = __builtin_amdgcn_mfma_f32_16x16x32_bf16(kf, qf[hc], sv[ps], 0, 0, 0);
            }
        }
        __builtin_amdgcn_s_setprio(0);
        int qrow = qt * 16 + li;
        unsigned qsz = (unsigned)((qrow & 7) << 4);
#pragma unroll
        for (int ps = 0; ps < 2; ps++) {
            float e0 = exp2f(sv[ps][0] * LOG2E);
            float e1 = exp2f(sv[ps][1] * LOG2E);
            float e2 = exp2f(sv[ps][2] * LOG2E);
            float e3 = exp2f(sv[ps][3] * LOG2E);
            psum += (e0 + e1) + (e2 + e3);
            uint2 pk;
            pk.x = (unsigned)f2bf(e0) | ((unsigned)f2bf(e1) << 16);
            pk.y = (unsigned)f2bf(e2) | ((unsigned)f2bf(e3) << 16);
            unsigned off = (unsigned)qrow * 128 +
                           (((unsigned)(phw * 64 + ps * 32 + g * 8)) ^ qsz);
            *reinterpret_cast<uint2*>((char*)Ps + off) = pk;
        }
        asm volatile("s_waitcnt lgkmcnt(0)\n\ts_barrier" ::: "memory");
        // dump the 8KB swizzled tile verbatim, fully coalesced
        {
            uint4 d = *reinterpret_cast<const uint4*>((char*)Ps + tid * 16);
            *reinterpret_cast<uint4*>(
                Pbd + ((size_t)(qtile * 64 + pt) << 12) + tid * 8) = d;
        }
    }
    psum += __shfl_xor(psum, 16);
    psum += __shfl_xor(psum, 32);
    if (lane < 16) sred[qt][phw][li] = psum;
    __syncthreads();
    if (phw == 0 && lane < 16) {
        float s = sred[qt][0][li] + sred[qt][1][li];
        sums[((size_t)ph0 * 8 + bd) * 4096 + q0 + qt * 16 + li] = s;
    }
#undef STAGE_K
}

// ---- B2: O[c][q] = (V . P^T) * linv[q] — 128x128 GEMM, BK=64, dbuf LDS, tiled-P B-staging ----
__global__ __launch_bounds__(256, 2) void k_pv(
        const u16* __restrict__ Lb, const u16* __restrict__ Rb,
        const u16* __restrict__ P, const float* __restrict__ sums,
        float* __restrict__ out, int bd0, int bdMask, int bdShift) {
    __shared__ u16 Tl[2][2][8192];     // [buf][A=V/B=P][...] 16KB each
    int bdl = (int)blockIdx.x & bdMask;
    int idx = (int)blockIdx.x >> bdShift;
    int mtile = idx & 3;               // 4 x 128 channels
    int ntile = idx >> 2;              // 32 x 128 q
    int bd = bd0 + bdl, dir = bd & 1, b = bd >> 1;
    const u16* V = (dir ? Lb : Rb) + (size_t)b * 512 * 4096;
    const u16* Pbd = P + ((size_t)bdl << 24);
    int q0 = ntile * 128, c0 = mtile * 128, qt0 = ntile * 2;
    int tid = threadIdx.x;
    int wv = __builtin_amdgcn_readfirstlane(tid >> 6);
    int lane = tid & 63, g = lane >> 4, li = lane & 15;
    int wr = wv >> 1, wc = wv & 1;     // wave tile: 64c x 64q

#define STAGE_PV(BUF, T)                                                                   \
    {                                                                                      \
        _Pragma("unroll") for (int r0 = 0; r0 < 4; r0++) {                                 \
            int o = r0 * 4096 + tid * 16;                                                  \
            int row = o >> 7, w = o & 127;                                                 \
            int sw = (w ^ ((row & 7) << 4)) >> 1;                                          \
            gload_lds16(V + (((size_t)(c0 + row)) << 12) + (T) * 64 + sw,                  \
                        &Tl[BUF][0][r0 * 2048 + wv * 512]);                                \
            gload_lds16(Pbd + (((size_t)((qt0 + (r0 >> 1)) * 64 + (T))) << 12) +           \
                            (r0 & 1) * 2048 + tid * 8,                                     \
                        &Tl[BUF][1][r0 * 2048 + wv * 512]);                                \
        }                                                                                  \
    }

    f32x4 acc[4][4];
#pragma unroll
    for (int i = 0; i < 4; i++)
#pragma unroll
        for (int j = 0; j < 4; j++) acc[i][j] = (f32x4){0.f, 0.f, 0.f, 0.f};

    STAGE_PV(0, 0)

    for (int t = 0; t < 64; t++) {
        asm volatile("s_waitcnt vmcnt(0) lgkmcnt(0)\n\ts_barrier" ::: "memory");
        if (t < 63) STAGE_PV((t + 1) & 1, t + 1)
        int buf = t & 1;
        bf16x8 af[4][2], bf[4][2];
#pragma unroll
        for (int mi = 0; mi < 4; mi++) {
            int row = wr * 64 + mi * 16 + li;
            unsigned rb = (unsigned)row * 128, sz = (unsigned)((row & 7) << 4);
#pragma unroll
            for (int kk = 0; kk < 2; kk++)
                af[mi][kk] = *reinterpret_cast<const bf16x8*>(
                    (char*)Tl[buf][0] + rb + (((unsigned)(kk * 64 + g * 16)) ^ sz));
        }
#pragma unroll
        for (int ni = 0; ni < 4; ni++) {
            int row = wc * 64 + ni * 16 + li;
            unsigned rb = (unsigned)row * 128, sz = (unsigned)((row & 7) << 4);
#pragma unroll
            for (int kk = 0; kk < 2; kk++)
                bf[ni][kk] = *reinterpret_cast<const bf16x8*>(
                    (char*)Tl[buf][1] + rb + (((unsigned)(kk * 64 + g * 16)) ^ sz));
        }
        __builtin_amdgcn_s_setprio(1);
#pragma unroll
        for (int kk = 0; kk < 2; kk++)
#pragma unroll
            for (int mi = 0; mi < 4; mi++)
#pragma unroll
                for (int ni = 0; ni < 4; ni++)
                    acc[mi][ni] = __builtin_amdgcn_mfma_f32_16x16x32_bf16(
                        af[mi][kk], bf[ni][kk], acc[mi][ni], 0, 0, 0);
        __builtin_amdgcn_s_setprio(0);
    }

    float* obase = out + ((size_t)(dir * 4 + b) * 1024 + 512) * 4096;
#pragma unroll
    for (int ni = 0; ni < 4; ni++) {
        int q = q0 + wc * 64 + ni * 16 + li;
        float s0 = sums[(size_t)bd * 4096 + q];
        float s1 = sums[((size_t)8 + bd) * 4096 + q];
        float linv = 1.0f / (s0 + s1);
#pragma unroll
        for (int mi = 0; mi < 4; mi++) {
            int c = c0 + wr * 64 + mi * 16 + g * 4;
#pragma unroll
            for (int r = 0; r < 4; r++)
                obase[(size_t)(c + r) * 4096 + q] = acc[mi][ni][r] * linv;
        }
    }
#undef STAGE_PV
}

// ---------------- D: homo softmax term, float4-vectorized, 2-pass (L2-hot reread) ----------------
__global__ __launch_bounds__(256) void k_homo(const float* __restrict__ L,
                                              const float* __restrict__ R,
                                              float* __restrict__ out) {
    __shared__ float4 red[16][16];
    int sb = blockIdx.x & 7, pblk = blockIdx.x >> 3;   // 64 pblks x 64 p
    int side = sb & 1, b = sb >> 1;
    const float* src = (side ? R : L) + (long)b * 1024 * 4096;
    float* o = out + (long)(side * 4 + b) * 1024 * 4096;
    int p4 = threadIdx.x & 15, cg = threadIdx.x >> 4;  // 16 f4-cols x 16 cgroups(32ch)
    int p = pblk * 64 + p4 * 4;
    const float* qo = src + p;
    const float* qt = src + (long)512 * 4096 + p;
    float4 sm = {0.f, 0.f, 0.f, 0.f};
    for (int c = cg * 32; c < cg * 32 + 32; c++) {
        float4 a = *reinterpret_cast<const float4*>(qo + (long)c * 4096);
        float4 t = *reinterpret_cast<const float4*>(qt + (long)c * 4096);
        sm.x += exp2f((a.x - t.x) * LOG2E);
        sm.y += exp2f((a.y - t.y) * LOG2E);
        sm.z += exp2f((a.z - t.z) * LOG2E);
        sm.w += exp2f((a.w - t.w) * LOG2E);
    }
    red[cg][p4] = sm;
    __syncthreads();
    float4 tot = {0.f, 0.f, 0.f, 0.f};
#pragma unroll
    for (int gR = 0; gR < 16; gR++) {
        float4 v = red[gR][p4];
        tot.x += v.x; tot.y += v.y; tot.z += v.z; tot.w += v.w;
    }
    float4 rinv = {1.0f / tot.x, 1.0f / tot.y, 1.0f / tot.z, 1.0f / tot.w};
    for (int c = cg * 32; c < cg * 32 + 32; c++) {
        float4 a = *reinterpret_cast<const float4*>(qo + (long)c * 4096);
        float4 t = *reinterpret_cast<const float4*>(qt + (long)c * 4096);
        float4* op = reinterpret_cast<float4*>(o + (long)(512 + c) * 4096 + p);
        float4 cur = *op;
        cur.x += t.x * exp2f((a.x - t.x) * LOG2E) * rinv.x;
        cur.y += t.y * exp2f((a.y - t.y) * LOG2E) * rinv.y;
        cur.z += t.z * exp2f((a.z - t.z) * LOG2E) * rinv.z;
        cur.w += t.w * exp2f((a.w - t.w) * LOG2E) * rinv.w;
        *op = cur;
    }
}

extern "C" void kernel_launch(void* const* d_in, const int* in_sizes, int n_in,
                              void* d_out, int out_size, void* d_ws, size_t ws_size,
                              hipStream_t stream) {
    const float* L  = (const float*)d_in[0];
    const float* R  = (const float*)d_in[1];
    const float* Wq = (const float*)d_in[2];
    const float* bq = (const float*)d_in[3];
    const float* Wk = (const float*)d_in[4];
    const float* bk = (const float*)d_in[5];
    float* out = (float*)d_out;
    char* ws = (char*)d_ws;

    size_t off = 0;
    u16* Wbq = (u16*)(ws + off); off += (size_t)128 * 512 * 2;
    u16* Wbk = (u16*)(ws + off); off += (size_t)128 * 512 * 2;
    u16* QL = (u16*)(ws + off); off += (size_t)NB * 4096 * 128 * 2;
    u16* KL = (u16*)(ws + off); off += (size_t)NB * 4096 * 128 * 2;
    u16* QR = (u16*)(ws + off); off += (size_t)NB * 4096 * 128 * 2;
    u16* KR = (u16*)(ws + off); off += (size_t)NB * 4096 * 128 * 2;
    u16* Lb = (u16*)(ws + off); off += (size_t)NB * 512 * 4096 * 2;
    u16* Rb = (u16*)(ws + off); off += (size_t)NB * 512 * 4096 * 2;
    float* sums = (float*)(ws + off); off += (size_t)2 * 8 * 4096 * 4;
    off = (off + 255) & ~(size_t)255;
    u16* Pb = (u16*)(ws + off);

    // chunking: prefer 4 bd per chunk (P chunk = 128MB, L3-resident); fallback 1 bd.
    size_t pchunk4 = (size_t)4 * 4096 * 4096 * 2;
    int nbd, bdShift;
    if (ws_size >= off + pchunk4) { nbd = 4; bdShift = 2; }
    else                          { nbd = 1; bdShift = 0; }
    int bdMask = nbd - 1;
    int nchunk = 8 / nbd;

    k_wcvt <<<64,    1024, 0, stream>>>(Wq, Wk, Wbq, Wbk);
    k_cvt  <<<16384, 256,  0, stream>>>(L, R, Lb, Rb, out);
    k_proj <<<1024,  256,  0, stream>>>(Lb, Rb, Wbq, Wbk, bq, bk, QL, KL, QR, KR);
    for (int c = 0; c < nchunk; c++) {
        k_qk <<<nbd * 128, 512, 0, stream>>>(QL, KL, QR, KR, Pb, sums,
                                             c * nbd, bdMask, bdShift);
        k_pv <<<nbd * 128, 256, 0, stream>>>(Lb, Rb, Pb, sums, out,
                                             c * nbd, bdMask, bdShift);
    }
    k_homo <<<512,   256,  0, stream>>>(L, R, out);
}

// Round 6
// 404.640 us; speedup vs baseline: 1.8886x; 1.0343x over previous
//
#include <hip/hip_runtime.h>
#include <hip/hip_bf16.h>

// (B, C2, H, W) = (4, 1024, 64, 64); CH=512, HID=128, P=4096
#define NB 4
#define LOG2E 1.4426950408889634f

typedef unsigned short u16;
typedef __attribute__((ext_vector_type(8))) short bf16x8;
typedef __attribute__((ext_vector_type(4))) float f32x4;

static __device__ __forceinline__ float bf2f(u16 u) {
    union { float f; unsigned v; } x; x.v = ((unsigned)u) << 16; return x.f;
}
static __device__ __forceinline__ u16 f2bf(float f) {
    unsigned v = __builtin_bit_cast(unsigned, f);
    return (u16)((v + 0x7FFFu + ((v >> 16) & 1u)) >> 16);
}
static __device__ __forceinline__ void gload_lds16(const u16* g, u16* l) {
    __builtin_amdgcn_global_load_lds(
        (const __attribute__((address_space(1))) unsigned*)(const void*)g,
        (__attribute__((address_space(3))) unsigned*)(void*)l, 16, 0, 0);
}

// ---------------- A0: W f32 -> bf16 ----------------
__global__ void k_wcvt(const float* __restrict__ Wq, const float* __restrict__ Wk,
                       u16* __restrict__ Wbq, u16* __restrict__ Wbk) {
    int i = blockIdx.x * 1024 + threadIdx.x;   // 65536
    Wbq[i] = f2bf(Wq[i]);
    Wbk[i] = f2bf(Wk[i]);
}

// ---- A1-fused: convert orig->bf16, copy orig->out, homo pass-1 (web = t*exp(a-t), partial sums) ----
// grid: 8 sb x 64 pblk x 4 cpart = 2048 blocks, 256 thr (16 p4-cols x 16 cgroups of 8ch)
__global__ __launch_bounds__(256) void k_cvtf(
        const float* __restrict__ L, const float* __restrict__ R,
        u16* __restrict__ Lb, u16* __restrict__ Rb,
        u16* __restrict__ web, float* __restrict__ sumsH, float* __restrict__ out) {
    __shared__ float4 red[16][16];
    int idx = blockIdx.x;
    int sb = idx & 7, pblk = (idx >> 3) & 63, cpart = idx >> 9;
    int side = sb & 1, b = sb >> 1;
    int osb = side * 4 + b;
    const float* src = (side ? R : L) + (size_t)b * 1024 * 4096;
    int tid = threadIdx.x;
    int p4 = tid & 15, cg = tid >> 4;
    int p = pblk * 64 + p4 * 4;
    int cbase = cpart * 128 + cg * 8;
    const float* ao = src + (size_t)cbase * 4096 + p;
    const float* at = src + (size_t)(512 + cbase) * 4096 + p;
    u16* lbdst = (side ? Rb : Lb) + ((size_t)b * 512 + cbase) * 4096 + p;
    float* odst = out + ((size_t)osb * 1024 + cbase) * 4096 + p;
    u16* wdst = web + ((size_t)osb * 512 + cbase) * 4096 + p;
    float4 sm = {0.f, 0.f, 0.f, 0.f};
#pragma unroll
    for (int cc = 0; cc < 8; cc++) {
        float4 a = *reinterpret_cast<const float4*>(ao + (size_t)cc * 4096);
        float4 t = *reinterpret_cast<const float4*>(at + (size_t)cc * 4096);
        ushort4 ub;
        ub.x = f2bf(a.x); ub.y = f2bf(a.y); ub.z = f2bf(a.z); ub.w = f2bf(a.w);
        *reinterpret_cast<ushort4*>(lbdst + (size_t)cc * 4096) = ub;
        *reinterpret_cast<float4*>(odst + (size_t)cc * 4096) = a;
        float4 e;
        e.x = exp2f((a.x - t.x) * LOG2E);
        e.y = exp2f((a.y - t.y) * LOG2E);
        e.z = exp2f((a.z - t.z) * LOG2E);
        e.w = exp2f((a.w - t.w) * LOG2E);
        sm.x += e.x; sm.y += e.y; sm.z += e.z; sm.w += e.w;
        ushort4 wb_;
        wb_.x = f2bf(t.x * e.x); wb_.y = f2bf(t.y * e.y);
        wb_.z = f2bf(t.z * e.z); wb_.w = f2bf(t.w * e.w);
        *reinterpret_cast<ushort4*>(wdst + (size_t)cc * 4096) = wb_;
    }
    red[cg][p4] = sm;
    __syncthreads();
    if (tid < 16) {
        float4 tot = {0.f, 0.f, 0.f, 0.f};
#pragma unroll
        for (int gR = 0; gR < 16; gR++) {
            float4 v = red[gR][tid];
            tot.x += v.x; tot.y += v.y; tot.z += v.z; tot.w += v.w;
        }
        *reinterpret_cast<float4*>(
            sumsH + ((size_t)cpart * 8 + osb) * 4096 + pblk * 64 + tid * 4) = tot;
    }
}

// ------- A1 (fallback, non-fused): f32 -> bf16 convert of first 512 channels; copy q_orig -------
__global__ void k_cvt(const float* __restrict__ L, const float* __restrict__ R,
                      u16* __restrict__ Lb, u16* __restrict__ Rb, float* __restrict__ out) {
    int i = blockIdx.x * 256 + threadIdx.x;
    int pq = i & 1023;
    int c = (i >> 10) & 511;
    int b = (i >> 19) & 3;
    int side = i >> 21;
    const float* src = (side ? R : L) + ((long)(b * 1024 + c) << 12) + (pq << 2);
    float4 v = *reinterpret_cast<const float4*>(src);
    ushort4 u;
    u.x = f2bf(v.x); u.y = f2bf(v.y); u.z = f2bf(v.z); u.w = f2bf(v.w);
    *reinterpret_cast<ushort4*>((side ? Rb : Lb) + ((long)(b * 512 + c) << 12) + (pq << 2)) = u;
    *reinterpret_cast<float4*>(out + ((long)(side * 4 + b) * 1024 + c) * 4096 + (pq << 2)) = v;
}

// ---------------- A2: projections via MFMA. Out: pos-major bf16 [p][128] ----------------
__global__ __launch_bounds__(256) void k_proj(
        const u16* __restrict__ Lb, const u16* __restrict__ Rb,
        const u16* __restrict__ Wbq, const u16* __restrict__ Wbk,
        const float* __restrict__ bq, const float* __restrict__ bk,
        u16* __restrict__ QL, u16* __restrict__ KL,
        u16* __restrict__ QR, u16* __restrict__ KR) {
    __shared__ u16 XT[2][64 * 40];
    int pj = blockIdx.x & 15, pt = blockIdx.x >> 4;
    int ty = pj >> 2, b = pj & 3;
    const u16* src; const u16* Wb; const float* bias; u16* dst;
    if (ty == 0)      { src = Lb; Wb = Wbq; bias = bq; dst = QL; }
    else if (ty == 1) { src = Rb; Wb = Wbk; bias = bk; dst = KL; }
    else if (ty == 2) { src = Rb; Wb = Wbq; bias = bq; dst = QR; }
    else              { src = Lb; Wb = Wbk; bias = bk; dst = KR; }
    const u16* X = src + (long)b * 512 * 4096 + pt * 64;
    int tid = threadIdx.x;
    int wv = __builtin_amdgcn_readfirstlane(tid >> 6);
    int lane = tid & 63, g = lane >> 4, li = lane & 15;

    f32x4 acc[8];
#pragma unroll
    for (int ob = 0; ob < 8; ob++)
#pragma unroll
        for (int r = 0; r < 4; r++) acc[ob][r] = bias[ob * 16 + g * 4 + r];

    int c_r = tid >> 3, j = tid & 7;
    bf16x8 gx = *reinterpret_cast<const bf16x8*>(X + (long)c_r * 4096 + j * 8);
#pragma unroll
    for (int k = 0; k < 8; k++) XT[0][(j * 8 + k) * 40 + c_r] = (u16)gx[k];
    __syncthreads();

    for (int cc = 0; cc < 16; cc++) {
        int buf = cc & 1;
        bf16x8 gn;
        if (cc < 15)
            gn = *reinterpret_cast<const bf16x8*>(X + (long)(cc * 32 + 32 + c_r) * 4096 + j * 8);
        bf16x8 xb = *reinterpret_cast<const bf16x8*>(&XT[buf][(wv * 16 + li) * 40 + g * 8]);
#pragma unroll
        for (int ob = 0; ob < 8; ob++) {
            bf16x8 aw = *reinterpret_cast<const bf16x8*>(Wb + (long)(ob * 16 + li) * 512 + cc * 32 + g * 8);
            acc[ob] = __builtin_amdgcn_mfma_f32_16x16x32_bf16(aw, xb, acc[ob], 0, 0, 0);
        }
        if (cc < 15) {
#pragma unroll
            for (int k = 0; k < 8; k++) XT[buf ^ 1][(j * 8 + k) * 40 + c_r] = (u16)gn[k];
        }
        __syncthreads();
    }
    u16* d = dst + ((long)b * 4096 + pt * 64 + wv * 16 + li) * 128;
#pragma unroll
    for (int ob = 0; ob < 8; ob++) {
        uint2 w;
        w.x = (unsigned)f2bf(acc[ob][0]) | ((unsigned)f2bf(acc[ob][1]) << 16);
        w.y = (unsigned)f2bf(acc[ob][2]) | ((unsigned)f2bf(acc[ob][3]) << 16);
        *reinterpret_cast<uint2*>(d + ob * 16 + g * 4) = w;
    }
}

// ---- B1: P = exp(Q.K^T), written as 8KB tiles [qtile][ptile][64q][64p] (swizzle baked).
//      p-split x2 across blocks; partial row-sums -> sums[ph0][bd][q]. ----
__global__ __launch_bounds__(512, 4) void k_qk(
        const u16* __restrict__ QL, const u16* __restrict__ KL,
        const u16* __restrict__ QR, const u16* __restrict__ KR,
        u16* __restrict__ P, float* __restrict__ sums,
        int bd0, int bdMask, int bdShift) {
    __shared__ u16 Kl[2][8192];       // [64p][128c] 16KB each, byte^=(p&7)<<4
    __shared__ u16 Ps[4096];          // [64q][64p] 8KB, byte^=(q&7)<<4
    __shared__ float sred[4][2][16];
    int bdl = (int)blockIdx.x & bdMask;
    int rest = (int)blockIdx.x >> bdShift;
    int qtile = rest & 63;
    int ph0 = rest >> 6;              // p-half: tiles [ph0*32, ph0*32+32)
    int bd = bd0 + bdl, dir = bd & 1, b = bd >> 1;
    const u16* Qt = (dir ? QR : QL) + (size_t)b * 4096 * 128;
    const u16* Kt = (dir ? KR : KL) + (size_t)b * 4096 * 128;
    u16* Pbd = P + ((size_t)bdl << 24);
    int q0 = qtile * 64;
    int tid = threadIdx.x;
    int wv = __builtin_amdgcn_readfirstlane(tid >> 6);
    int lane = tid & 63, g = lane >> 4, li = lane & 15;
    int qt = wv >> 1, phw = wv & 1;

#define STAGE_K(BUF, PT)                                                                   \
    {                                                                                      \
        _Pragma("unroll") for (int r0 = 0; r0 < 2; r0++) {                                 \
            int o = r0 * 8192 + tid * 16;                                                  \
            int row = o >> 8, w = o & 255;                                                 \
            int sw = (w ^ ((row & 7) << 4)) >> 1;                                          \
            gload_lds16(Kt + (((size_t)((PT) * 64 + row)) << 7) + sw,                      \
                        &Kl[BUF][r0 * 4096 + wv * 512]);                                   \
        }                                                                                  \
    }

    bf16x8 qf[4];
#pragma unroll
    for (int hc = 0; hc < 4; hc++)
        qf[hc] = *reinterpret_cast<const bf16x8*>(
            Qt + (size_t)(q0 + qt * 16 + li) * 128 + hc * 32 + g * 8);
    float psum = 0.f;
    STAGE_K(0, ph0 * 32)

    for (int tt = 0; tt < 32; tt++) {
        int pt = ph0 * 32 + tt;
        if (tt == 0) asm volatile("s_waitcnt vmcnt(0) lgkmcnt(0)\n\ts_barrier" ::: "memory");
        else         asm volatile("s_waitcnt vmcnt(1) lgkmcnt(0)\n\ts_barrier" ::: "memory");
        if (tt < 31) STAGE_K((tt + 1) & 1, pt + 1)
        int buf = tt & 1;
        f32x4 sv[2];
        sv[0] = (f32x4){0.f, 0.f, 0.f, 0.f};
        sv[1] = (f32x4){0.f, 0.f, 0.f, 0.f};
        __builtin_amdgcn_s_setprio(1);
#pragma unroll
        for (int ps = 0; ps < 2; ps++) {
            int row = phw * 32 + ps * 16 + li;
            unsigned rb = (unsigned)row * 256;
            unsigned sz = (unsigned)((row & 7) << 4);
#pragma unroll
            for (int hc = 0; hc < 4; hc++) {
                bf16x8 kf = *reinterpret_cast<const bf16x8*>(
                    (char*)Kl[buf] + rb + (((unsigned)(hc * 64 + g * 16)) ^ sz));
                sv[ps] = __builtin_amdgcn_mfma_f32_16x16x32_bf16(kf, qf[hc], sv[ps], 0, 0, 0);
            }
        }
        __builtin_amdgcn_s_setprio(0);
        int qrow = qt * 16 + li;
        unsigned qsz = (unsigned)((qrow & 7) << 4);
#pragma unroll
        for (int ps = 0; ps < 2; ps++) {
            float e0 = exp2f(sv[ps][0] * LOG2E);
            float e1 = exp2f(sv[ps][1] * LOG2E);
            float e2 = exp2f(sv[ps][2] * LOG2E);
            float e3 = exp2f(sv[ps][3] * LOG2E);
            psum += (e0 + e1) + (e2 + e3);
            uint2 pk;
            pk.x = (unsigned)f2bf(e0) | ((unsigned)f2bf(e1) << 16);
            pk.y = (unsigned)f2bf(e2) | ((unsigned)f2bf(e3) << 16);
            unsigned off = (unsigned)qrow * 128 +
                           (((unsigned)(phw * 64 + ps * 32 + g * 8)) ^ qsz);
            *reinterpret_cast<uint2*>((char*)Ps + off) = pk;
        }
        asm volatile("s_waitcnt lgkmcnt(0)\n\ts_barrier" ::: "memory");
        {
            uint4 d = *reinterpret_cast<const uint4*>((char*)Ps + tid * 16);
            *reinterpret_cast<uint4*>(
                Pbd + ((size_t)(qtile * 64 + pt) << 12) + tid * 8) = d;
        }
    }
    psum += __shfl_xor(psum, 16);
    psum += __shfl_xor(psum, 32);
    if (lane < 16) sred[qt][phw][li] = psum;
    __syncthreads();
    if (phw == 0 && lane < 16) {
        float s = sred[qt][0][li] + sred[qt][1][li];
        sums[((size_t)ph0 * 8 + bd) * 4096 + q0 + qt * 16 + li] = s;
    }
#undef STAGE_K
}

// ---- B2: O[c][q] = (V.P^T)*linv[q] (+ fused homo term when FUSEH) ----
template<int FUSEH>
__global__ __launch_bounds__(256, 2) void k_pv(
        const u16* __restrict__ Lb, const u16* __restrict__ Rb,
        const u16* __restrict__ P, const float* __restrict__ sums,
        const u16* __restrict__ web, const float* __restrict__ sumsH,
        float* __restrict__ out, int bd0, int bdMask, int bdShift) {
    __shared__ u16 Tl[2][2][8192];     // [buf][A=V/B=P][...] 16KB each
    int bdl = (int)blockIdx.x & bdMask;
    int idx = (int)blockIdx.x >> bdShift;
    int mtile = idx & 3;               // 4 x 128 channels
    int ntile = idx >> 2;              // 32 x 128 q
    int bd = bd0 + bdl, dir = bd & 1, b = bd >> 1;
    int osb = dir * 4 + b;
    const u16* V = (dir ? Lb : Rb) + (size_t)b * 512 * 4096;
    const u16* Pbd = P + ((size_t)bdl << 24);
    int q0 = ntile * 128, c0 = mtile * 128, qt0 = ntile * 2;
    int tid = threadIdx.x;
    int wv = __builtin_amdgcn_readfirstlane(tid >> 6);
    int lane = tid & 63, g = lane >> 4, li = lane & 15;
    int wr = wv >> 1, wc = wv & 1;     // wave tile: 64c x 64q

#define STAGE_PV(BUF, T)                                                                   \
    {                                                                                      \
        _Pragma("unroll") for (int r0 = 0; r0 < 4; r0++) {                                 \
            int o = r0 * 4096 + tid * 16;                                                  \
            int row = o >> 7, w = o & 127;                                                 \
            int sw = (w ^ ((row & 7) << 4)) >> 1;                                          \
            gload_lds16(V + (((size_t)(c0 + row)) << 12) + (T) * 64 + sw,                  \
                        &Tl[BUF][0][r0 * 2048 + wv * 512]);                                \
            gload_lds16(Pbd + (((size_t)((qt0 + (r0 >> 1)) * 64 + (T))) << 12) +           \
                            (r0 & 1) * 2048 + tid * 8,                                     \
                        &Tl[BUF][1][r0 * 2048 + wv * 512]);                                \
        }                                                                                  \
    }

    f32x4 acc[4][4];
#pragma unroll
    for (int i = 0; i < 4; i++)
#pragma unroll
        for (int j = 0; j < 4; j++) acc[i][j] = (f32x4){0.f, 0.f, 0.f, 0.f};

    STAGE_PV(0, 0)

    for (int t = 0; t < 64; t++) {
        asm volatile("s_waitcnt vmcnt(0) lgkmcnt(0)\n\ts_barrier" ::: "memory");
        if (t < 63) STAGE_PV((t + 1) & 1, t + 1)
        int buf = t & 1;
        bf16x8 af[4][2], bf[4][2];
#pragma unroll
        for (int mi = 0; mi < 4; mi++) {
            int row = wr * 64 + mi * 16 + li;
            unsigned rb = (unsigned)row * 128, sz = (unsigned)((row & 7) << 4);
#pragma unroll
            for (int kk = 0; kk < 2; kk++)
                af[mi][kk] = *reinterpret_cast<const bf16x8*>(
                    (char*)Tl[buf][0] + rb + (((unsigned)(kk * 64 + g * 16)) ^ sz));
        }
#pragma unroll
        for (int ni = 0; ni < 4; ni++) {
            int row = wc * 64 + ni * 16 + li;
            unsigned rb = (unsigned)row * 128, sz = (unsigned)((row & 7) << 4);
#pragma unroll
            for (int kk = 0; kk < 2; kk++)
                bf[ni][kk] = *reinterpret_cast<const bf16x8*>(
                    (char*)Tl[buf][1] + rb + (((unsigned)(kk * 64 + g * 16)) ^ sz));
        }
        __builtin_amdgcn_s_setprio(1);
#pragma unroll
        for (int kk = 0; kk < 2; kk++)
#pragma unroll
            for (int mi = 0; mi < 4; mi++)
#pragma unroll
                for (int ni = 0; ni < 4; ni++)
                    acc[mi][ni] = __builtin_amdgcn_mfma_f32_16x16x32_bf16(
                        af[mi][kk], bf[ni][kk], acc[mi][ni], 0, 0, 0);
        __builtin_amdgcn_s_setprio(0);
    }

    float* obase = out + ((size_t)osb * 1024 + 512) * 4096;
    const u16* wb = web + (size_t)osb * 512 * 4096;
#pragma unroll
    for (int ni = 0; ni < 4; ni++) {
        int q = q0 + wc * 64 + ni * 16 + li;
        float s0 = sums[(size_t)bd * 4096 + q];
        float s1 = sums[((size_t)8 + bd) * 4096 + q];
        float linv = 1.0f / (s0 + s1);
        float hinv = 0.f;
        if (FUSEH) {
            float hs = sumsH[(size_t)osb * 4096 + q] +
                       sumsH[((size_t)8 + osb) * 4096 + q] +
                       sumsH[((size_t)16 + osb) * 4096 + q] +
                       sumsH[((size_t)24 + osb) * 4096 + q];
            hinv = 1.0f / hs;
        }
#pragma unroll
        for (int mi = 0; mi < 4; mi++) {
            int c = c0 + wr * 64 + mi * 16 + g * 4;
#pragma unroll
            for (int r = 0; r < 4; r++) {
                float v = acc[mi][ni][r] * linv;
                if (FUSEH) v += bf2f(wb[(size_t)(c + r) * 4096 + q]) * hinv;
                obase[(size_t)(c + r) * 4096 + q] = v;
            }
        }
    }
#undef STAGE_PV
}

// ---------------- D (fallback): homo softmax term, float4, 2-pass ----------------
__global__ __launch_bounds__(256) void k_homo(const float* __restrict__ L,
                                              const float* __restrict__ R,
                                              float* __restrict__ out) {
    __shared__ float4 red[16][16];
    int sb = blockIdx.x & 7, pblk = blockIdx.x >> 3;
    int side = sb & 1, b = sb >> 1;
    const float* src = (side ? R : L) + (long)b * 1024 * 4096;
    float* o = out + (long)(side * 4 + b) * 1024 * 4096;
    int p4 = threadIdx.x & 15, cg = threadIdx.x >> 4;
    int p = pblk * 64 + p4 * 4;
    const float* qo = src + p;
    const float* qt = src + (long)512 * 4096 + p;
    float4 sm = {0.f, 0.f, 0.f, 0.f};
    for (int c = cg * 32; c < cg * 32 + 32; c++) {
        float4 a = *reinterpret_cast<const float4*>(qo + (long)c * 4096);
        float4 t = *reinterpret_cast<const float4*>(qt + (long)c * 4096);
        sm.x += exp2f((a.x - t.x) * LOG2E);
        sm.y += exp2f((a.y - t.y) * LOG2E);
        sm.z += exp2f((a.z - t.z) * LOG2E);
        sm.w += exp2f((a.w - t.w) * LOG2E);
    }
    red[cg][p4] = sm;
    __syncthreads();
    float4 tot = {0.f, 0.f, 0.f, 0.f};
#pragma unroll
    for (int gR = 0; gR < 16; gR++) {
        float4 v = red[gR][p4];
        tot.x += v.x; tot.y += v.y; tot.z += v.z; tot.w += v.w;
    }
    float4 rinv = {1.0f / tot.x, 1.0f / tot.y, 1.0f / tot.z, 1.0f / tot.w};
    for (int c = cg * 32; c < cg * 32 + 32; c++) {
        float4 a = *reinterpret_cast<const float4*>(qo + (long)c * 4096);
        float4 t = *reinterpret_cast<const float4*>(qt + (long)c * 4096);
        float4* op = reinterpret_cast<float4*>(o + (long)(512 + c) * 4096 + p);
        float4 cur = *op;
        cur.x += t.x * exp2f((a.x - t.x) * LOG2E) * rinv.x;
        cur.y += t.y * exp2f((a.y - t.y) * LOG2E) * rinv.y;
        cur.z += t.z * exp2f((a.z - t.z) * LOG2E) * rinv.z;
        cur.w += t.w * exp2f((a.w - t.w) * LOG2E) * rinv.w;
        *op = cur;
    }
}

extern "C" void kernel_launch(void* const* d_in, const int* in_sizes, int n_in,
                              void* d_out, int out_size, void* d_ws, size_t ws_size,
                              hipStream_t stream) {
    const float* L  = (const float*)d_in[0];
    const float* R  = (const float*)d_in[1];
    const float* Wq = (const float*)d_in[2];
    const float* bq = (const float*)d_in[3];
    const float* Wk = (const float*)d_in[4];
    const float* bk = (const float*)d_in[5];
    float* out = (float*)d_out;
    char* ws = (char*)d_ws;

    size_t off = 0;
    u16* Wbq = (u16*)(ws + off); off += (size_t)128 * 512 * 2;
    u16* Wbk = (u16*)(ws + off); off += (size_t)128 * 512 * 2;
    u16* QL = (u16*)(ws + off); off += (size_t)NB * 4096 * 128 * 2;
    u16* KL = (u16*)(ws + off); off += (size_t)NB * 4096 * 128 * 2;
    u16* QR = (u16*)(ws + off); off += (size_t)NB * 4096 * 128 * 2;
    u16* KR = (u16*)(ws + off); off += (size_t)NB * 4096 * 128 * 2;
    u16* Lb = (u16*)(ws + off); off += (size_t)NB * 512 * 4096 * 2;
    u16* Rb = (u16*)(ws + off); off += (size_t)NB * 512 * 4096 * 2;
    float* sums = (float*)(ws + off); off += (size_t)2 * 8 * 4096 * 4;
    float* sumsH = (float*)(ws + off); off += (size_t)4 * 8 * 4096 * 4;
    size_t off_nofuse = off;
    u16* web = (u16*)(ws + off); off += (size_t)8 * 512 * 4096 * 2;
    off = (off + 255) & ~(size_t)255;
    size_t pchunk4 = (size_t)4 * 4096 * 4096 * 2;
    size_t pchunk1 = (size_t)4096 * 4096 * 2;

    k_wcvt <<<64, 1024, 0, stream>>>(Wq, Wk, Wbq, Wbk);

    if (ws_size >= off + pchunk4) {
        // ---- fused-homo path, 4bd chunks ----
        u16* Pb = (u16*)(ws + off);
        k_cvtf <<<2048, 256, 0, stream>>>(L, R, Lb, Rb, web, sumsH, out);
        k_proj <<<1024, 256, 0, stream>>>(Lb, Rb, Wbq, Wbk, bq, bk, QL, KL, QR, KR);
        for (int c = 0; c < 2; c++) {
            k_qk    <<<512, 512, 0, stream>>>(QL, KL, QR, KR, Pb, sums, c * 4, 3, 2);
            k_pv<1> <<<512, 256, 0, stream>>>(Lb, Rb, Pb, sums, web, sumsH, out, c * 4, 3, 2);
        }
    } else {
        // ---- fallback: separate homo kernel ----
        int nbd, bdShift;
        size_t poff = (off_nofuse + 255) & ~(size_t)255;
        if (ws_size >= poff + pchunk4) { nbd = 4; bdShift = 2; }
        else                           { nbd = 1; bdShift = 0; }
        int bdMask = nbd - 1, nchunk = 8 / nbd;
        u16* Pb = (u16*)(ws + poff);
        k_cvt  <<<16384, 256, 0, stream>>>(L, R, Lb, Rb, out);
        k_proj <<<1024,  256, 0, stream>>>(Lb, Rb, Wbq, Wbk, bq, bk, QL, KL, QR, KR);
        for (int c = 0; c < nchunk; c++) {
            k_qk    <<<nbd * 128, 512, 0, stream>>>(QL, KL, QR, KR, Pb, sums,
                                                    c * nbd, bdMask, bdShift);
            k_pv<0> <<<nbd * 128, 256, 0, stream>>>(Lb, Rb, Pb, sums, web, sumsH, out,
                                                    c * nbd, bdMask, bdShift);
        }
        k_homo <<<512, 256, 0, stream>>>(L, R, out);
    }
}